// Round 18
// baseline (53.800 us; speedup 1.0000x reference)
//
#include <hip/hip_runtime.h>
#include <hip/hip_bf16.h>

typedef unsigned short u16;
typedef unsigned int u32;
typedef __bf16 bf16;
typedef bf16 bf16x8 __attribute__((ext_vector_type(8)));
typedef float f32x4 __attribute__((ext_vector_type(4)));

#define B_ 8
#define T_ 2048
#define C_ 768
#define MB 1048576ull
#define SCALE_Q 0.1803368867f   /* 0.125 * log2(e): folds 1/sqrt(64) and exp->exp2 */
#define NEG_INF (-__builtin_inff())

#define AS1 __attribute__((address_space(1)))
#define AS3 __attribute__((address_space(3)))

__device__ __forceinline__ void g2l16(const void* g, void* l) {
  __builtin_amdgcn_global_load_lds((AS1 const void*)g, (AS3 void*)l, 16, 0, 0);
}
__device__ __forceinline__ u16 bf2u(bf16 h) {
  union { bf16 h; u16 u; } x; x.h = h; return x.u;
}
#define MFMA16(A, B, C) __builtin_amdgcn_mfma_f32_16x16x32_bf16((A), (B), (C), 0, 0, 0)
#define SBAR() __builtin_amdgcn_sched_barrier(0)
#define BARRIER() do { SBAR(); __builtin_amdgcn_s_barrier(); SBAR(); } while (0)

// ---------------------------------------------------------------------------
// Kernel 1: pre-swizzled Wt image, DOUBLE-STEP packed. (Unchanged.)
// ---------------------------------------------------------------------------
__global__ __launch_bounds__(256) void prepw_kernel(const float* __restrict__ Wq,
                                                    const float* __restrict__ Wk,
                                                    const float* __restrict__ Wv,
                                                    u16* __restrict__ wt_img) {
  int tid = blockIdx.x * 256 + threadIdx.x;        // 3*768*64 = 147456 exactly
  int jj = tid & 63;
  int k  = (tid >> 6) % C_;
  int m  = tid / (64 * C_);
  const float* W = (m == 0) ? Wq : (m == 1 ? Wk : Wv);
  bf16 hv = (bf16)W[k * 64 + jj];
  int s2 = k >> 6, kk2 = k & 63, j = m * 64 + jj;
  int byteoff = (s2 * 192 + j) * 128 + ((2 * kk2) ^ ((j & 7) << 4));
  *(u16*)((char*)wt_img + byteoff) = bf2u(hv);
}

// ---------------------------------------------------------------------------
// Kernel 2: projections, 2 BLOCKS/CU. (Round-17 proven version, unchanged.)
// ---------------------------------------------------------------------------
__global__ __launch_bounds__(512) void proj_kernel(const float* __restrict__ x,
                                                   const u16* __restrict__ wt_img,
                                                   u16* __restrict__ q_ws,
                                                   u16* __restrict__ k_img,
                                                   u16* __restrict__ vt_img) {
  __shared__ __align__(16) char xt[2][8192];       // [half][32 rows][128B] f32, swizzled
  __shared__ __align__(16) char wt[2][24576];
  int tid = threadIdx.x, lane = tid & 63, w = tid >> 6;
  int wm = w & 1, wn = w >> 1;           // wm: 16-row half; wn: 48-col band
  int r0 = blockIdx.x * 32;
  int c = lane & 15, g = lane >> 4;

  f32x4 acc[3];
#pragma unroll
  for (int i = 0; i < 3; ++i) acc[i] = (f32x4){0.f, 0.f, 0.f, 0.f};

  int xrow = (tid >> 3) & 31, xch = tid & 7, xhalf = tid >> 8;
  const float* srcx = x + (size_t)(r0 + xrow) * C_ + xhalf * 32 + ((xch ^ (xrow & 7)) << 2);

  auto STAGE = [&](int s, int bs) {
    const char* wsrc = (const char*)wt_img + s * 24576;
#pragma unroll
    for (int i = 0; i < 3; ++i)
      g2l16(wsrc + (i * 512 + tid) * 16, wt[bs] + (i * 512 + tid) * 16);
    g2l16(srcx + s * 64, xt[bs] + tid * 16);
  };

  STAGE(0, 0);

  int arow = wm * 16 + c;
  int ax = arow & 7;

  for (int s2 = 0; s2 < 12; ++s2) {
    int cur = s2 & 1;
    if (s2 < 11) {
      STAGE(s2 + 1, cur ^ 1);
      asm volatile("s_waitcnt vmcnt(4)" ::: "memory");   // stage(s2) landed
    } else {
      asm volatile("s_waitcnt vmcnt(0)" ::: "memory");
    }
    BARRIER();                           // stage(s2) certified landed (all waves)
    const char* x0 = xt[cur] + arow * 128;
    const char* x1 = x0 + 4096;
    f32x4 f0 = *(const f32x4*)(x0 + (((2 * g)     ^ ax) << 4));
    f32x4 f1 = *(const f32x4*)(x0 + (((2 * g + 1) ^ ax) << 4));
    f32x4 f2 = *(const f32x4*)(x1 + (((2 * g)     ^ ax) << 4));
    f32x4 f3 = *(const f32x4*)(x1 + (((2 * g + 1) ^ ax) << 4));
    bf16x8 af0, af1;
    af0[0] = (bf16)f0[0]; af0[1] = (bf16)f0[1]; af0[2] = (bf16)f0[2]; af0[3] = (bf16)f0[3];
    af0[4] = (bf16)f1[0]; af0[5] = (bf16)f1[1]; af0[6] = (bf16)f1[2]; af0[7] = (bf16)f1[3];
    af1[0] = (bf16)f2[0]; af1[1] = (bf16)f2[1]; af1[2] = (bf16)f2[2]; af1[3] = (bf16)f2[3];
    af1[4] = (bf16)f3[0]; af1[5] = (bf16)f3[1]; af1[6] = (bf16)f3[2]; af1[7] = (bf16)f3[3];
    const char* bb = wt[cur];
#pragma unroll
    for (int nt = 0; nt < 3; ++nt) {
      int brow = wn * 48 + nt * 16 + c;
      const char* br = bb + brow * 128;
      int bx = (brow & 7) << 4;
      bf16x8 b0 = *(const bf16x8*)(br + ((16 * g) ^ bx));
      bf16x8 b1 = *(const bf16x8*)(br + ((64 + 16 * g) ^ bx));
      acc[nt] = MFMA16(af0, b0, acc[nt]);
      acc[nt] = MFMA16(af1, b1, acc[nt]);
    }
    if (s2 < 11) {
      asm volatile("s_waitcnt lgkmcnt(0)" ::: "memory");
      BARRIER();                         // readers done -> buffer cur reusable
    }
  }

  // epilogue: D layout col = lane&15, row = (lane>>4)*4 + reg
#pragma unroll
  for (int nt = 0; nt < 3; ++nt) {
    int gc = wn * 48 + nt * 16;
    int m = gc >> 6;
    int h = (gc & 63) + c;
#pragma unroll
    for (int reg = 0; reg < 4; ++reg) {
      int r = r0 + wm * 16 + g * 4 + reg;   // token index
      float val = acc[nt][reg];
      int bb2 = r >> 11, rr = r & 2047, t = rr >> 6;
      if (m == 0) {
        q_ws[(size_t)r * 64 + h] = bf2u((bf16)(val * SCALE_Q));
      } else if (m == 1) {
        int ntk = (rr >> 4) & 3, ck = rr & 15;
        int jp = h >> 5, gg = (h >> 3) & 3, jj = h & 7;
        k_img[((size_t)(bb2 * 32 + t)) * 4096 + ntk * 1024 + jp * 512 + gg * 128 + ck * 8 + jj] = bf2u((bf16)val);
      } else {
        int ht = h >> 4, cv = h & 15;
        int jpv = (rr >> 5) & 1, gv = (rr >> 3) & 3, jv = rr & 7;
        vt_img[((size_t)(bb2 * 32 + t)) * 4096 + ht * 1024 + jpv * 512 + gv * 128 + cv * 8 + jv] = bf2u((bf16)val);
      }
    }
  }
}

// ---------------------------------------------------------------------------
// Kernel 3: causal flash attention, FUSED split-KV + in-LDS merge,
// CROSS-TILE K DOUBLE-BUFFER (named kA/kB, static indexing) + LPT block
// order (heavy q-tiles first) + no sched_barriers (compiler pipelines).
// Next tile's 8 contiguous K loads issue right after current QK^T and hide
// under softmax+PV. V keeps half0/half1 register split (peak VGPR control).
// ---------------------------------------------------------------------------
struct KF { bf16x8 f[4][2]; };

__device__ __forceinline__ void load_kf(KF& k, const u16* kbase, int t) {
#pragma unroll
  for (int nt = 0; nt < 4; ++nt)
#pragma unroll
    for (int jp = 0; jp < 2; ++jp)
      k.f[nt][jp] = *(const bf16x8*)(kbase + (size_t)t * 4096 + nt * 1024 + jp * 512);
}

__device__ __forceinline__ void tile_body3(int t, const KF& kU, KF& kP, bool doPre,
                                           int t0, int nkt, int q0,
                                           const u16* kbase, const u16* vbase,
                                           const bf16x8& qb0, const bf16x8& qb1,
                                           int c, int g, char* pw,
                                           f32x4 (&accO)[4], float& mrun, float& lrun) {
  // S^T[kpos][q] = K . Q^T from the CURRENT buffer (kU dies here)
  f32x4 st[4];
#pragma unroll
  for (int nt = 0; nt < 4; ++nt) {
    f32x4 z = (f32x4){0.f, 0.f, 0.f, 0.f};
    z = MFMA16(kU.f[nt][0], qb0, z);
    st[nt] = MFMA16(kU.f[nt][1], qb1, z);
  }
  // prefetch NEXT tile's K into the other buffer; hidden under softmax+PV
  if (doPre) load_kf(kP, kbase, t + 1);
  // V half 0 (kv slots 0-31)
  bf16x8 vf[4];
#pragma unroll
  for (int ht = 0; ht < 4; ++ht)
    vf[ht] = *(const bf16x8*)(vbase + (size_t)t * 4096 + ht * 1024);
  int tt = t0 + t;
  if (tt == nkt - 1) {   // diagonal tile: mask kpos > q
    int qg = q0 + c, kb2 = tt * 64 + g * 4;
#pragma unroll
    for (int nt = 0; nt < 4; ++nt)
#pragma unroll
      for (int reg = 0; reg < 4; ++reg)
        if (kb2 + nt * 16 + reg > qg) st[nt][reg] = NEG_INF;
  }
  // lane-local softmax over 16 held kpos + cross-group (xor16, xor32)
  float smax = st[0][0];
#pragma unroll
  for (int nt = 0; nt < 4; ++nt)
#pragma unroll
    for (int reg = 0; reg < 4; ++reg) smax = fmaxf(smax, st[nt][reg]);
  smax = fmaxf(smax, __shfl_xor(smax, 16));
  smax = fmaxf(smax, __shfl_xor(smax, 32));
  float mnew = fmaxf(mrun, smax);
  float sf = exp2f(mrun - mnew);
  float rsum = 0.f;
  u32 pk[4][2];
#pragma unroll
  for (int nt = 0; nt < 4; ++nt)
#pragma unroll
    for (int jp = 0; jp < 2; ++jp) {
      float p0 = exp2f(st[nt][2 * jp] - mnew);
      float p1 = exp2f(st[nt][2 * jp + 1] - mnew);
      rsum += p0 + p1;
      pk[nt][jp] = (u32)bf2u((bf16)p0) | ((u32)bf2u((bf16)p1) << 16);
    }
  rsum += __shfl_xor(rsum, 16);
  rsum += __shfl_xor(rsum, 32);
  lrun = lrun * sf + rsum;
  mrun = mnew;
#pragma unroll
  for (int ht = 0; ht < 4; ++ht) accO[ht] *= sf;
  // P (q-row c, 64 kpos) -> wave-private swizzled LDS row, packed b32 writes
  int swz = (c & 7) << 4;
#pragma unroll
  for (int nt = 0; nt < 4; ++nt)
#pragma unroll
    for (int jp = 0; jp < 2; ++jp) {
      int kpos = nt * 16 + g * 4 + 2 * jp;
      *(u32*)(pw + ((2 * kpos) ^ swz)) = pk[nt][jp];
    }
  // PV half 0
  bf16x8 pf0 = *(const bf16x8*)(pw + ((16 * g) ^ swz));
#pragma unroll
  for (int ht = 0; ht < 4; ++ht)
    accO[ht] = MFMA16(vf[ht], pf0, accO[ht]);
  // V half 1 (kv slots 32-63), PV half 1
#pragma unroll
  for (int ht = 0; ht < 4; ++ht)
    vf[ht] = *(const bf16x8*)(vbase + (size_t)t * 4096 + ht * 1024 + 512);
  bf16x8 pf1 = *(const bf16x8*)(pw + ((64 + 16 * g) ^ swz));
#pragma unroll
  for (int ht = 0; ht < 4; ++ht)
    accO[ht] = MFMA16(vf[ht], pf1, accO[ht]);
}

__global__ __launch_bounds__(512, 4) void attn_kernel(const u16* __restrict__ q_ws,
                                                      const u16* __restrict__ k_img,
                                                      const u16* __restrict__ vt_img,
                                                      float* __restrict__ out) {
  __shared__ __align__(16) char sP[8 * 2048];       // wave-private P tiles
  __shared__ float po_s[8][64][17];                 // padded: conflict-free both ways
  __shared__ float2 ml_s[8][16];
  int tid = threadIdx.x, lane = tid & 63, w = tid >> 6;
  int bid = blockIdx.x;
  int b = bid & 7;                       // batch -> XCD
  int qt = 127 - (bid >> 3);             // LPT: heavy q-tiles dispatch FIRST
  int nkt = (qt >> 2) + 1;               // 1..32 KV tiles
  int CH = (nkt + 7) >> 3;               // 1..4 tiles per wave
  int t0 = w * CH;
  int n = nkt - t0; if (n < 0) n = 0; if (n > CH) n = CH;
  int q0 = qt * 16;
  int c = lane & 15, g = lane >> 4;

  // Q as B-operand: col = q = c, k(h) = 8g+j; q pre-scaled by 0.125*log2e
  const u16* qb_p = q_ws + ((size_t)b * T_ + q0 + c) * 64 + 8 * g;
  bf16x8 qb0 = *(const bf16x8*)qb_p;
  bf16x8 qb1 = *(const bf16x8*)(qb_p + 32);

  const u16* kbase = k_img + ((size_t)(b * 32 + t0)) * 4096 + lane * 8;
  const u16* vbase = vt_img + ((size_t)(b * 32 + t0)) * 4096 + lane * 8;

  f32x4 accO[4];
#pragma unroll
  for (int i = 0; i < 4; ++i) accO[i] = (f32x4){0.f, 0.f, 0.f, 0.f};
  float mrun = NEG_INF, lrun = 0.f;
  char* pw = sP + w * 2048 + c * 128;

  KF kA, kB;
  if (n > 0) load_kf(kA, kbase, 0);
  /* explicit bodies, named dbuf structs — all register indexing static */
  if (n > 0) tile_body3(0, kA, kB, n > 1, t0, nkt, q0, kbase, vbase, qb0, qb1, c, g, pw, accO, mrun, lrun);
  if (n > 1) tile_body3(1, kB, kA, n > 2, t0, nkt, q0, kbase, vbase, qb0, qb1, c, g, pw, accO, mrun, lrun);
  if (n > 2) tile_body3(2, kA, kB, n > 3, t0, nkt, q0, kbase, vbase, qb0, qb1, c, g, pw, accO, mrun, lrun);
  if (n > 3) tile_body3(3, kB, kA, false, t0, nkt, q0, kbase, vbase, qb0, qb1, c, g, pw, accO, mrun, lrun);

  // publish partials to LDS (active waves only)
  if (n > 0) {
#pragma unroll
    for (int ht = 0; ht < 4; ++ht)
#pragma unroll
      for (int reg = 0; reg < 4; ++reg)
        po_s[w][ht * 16 + g * 4 + reg][c] = accO[ht][reg];
    if (g == 0) ml_s[w][c] = make_float2(mrun, lrun);
  }
  __syncthreads();

  // in-block merge: wave w handles q-rows {w, w+8}; lane holds h = lane.
  int nact = (nkt + CH - 1) / CH;        // number of active chunk waves
#pragma unroll
  for (int half = 0; half < 2; ++half) {
    int qq = w + half * 8;
    float M = NEG_INF;
#pragma unroll
    for (int ci = 0; ci < 8; ++ci)
      if (ci < nact) M = fmaxf(M, ml_s[ci][qq].x);
    float L = 0.f, s = 0.f;
#pragma unroll
    for (int ci = 0; ci < 8; ++ci)
      if (ci < nact) {
        float2 mlv = ml_s[ci][qq];
        float wg = exp2f(mlv.x - M);
        L += wg * mlv.y;
        s += wg * po_s[ci][lane][qq];
      }
    out[((size_t)b * T_ + q0 + qq) * 64 + lane] = s / L;
  }
}

// ---------------------------------------------------------------------------
extern "C" void kernel_launch(void* const* d_in, const int* in_sizes, int n_in,
                              void* d_out, int out_size, void* d_ws, size_t ws_size,
                              hipStream_t stream) {
  const float* x  = (const float*)d_in[0];
  const float* Wk = (const float*)d_in[1];
  const float* Wq = (const float*)d_in[2];
  const float* Wv = (const float*)d_in[3];
  char* ws = (char*)d_ws;
  u16* q_ws   = (u16*)(ws);                //  0MB: [16384][64] bf16 (q * 0.125*log2e)
  u16* k_img  = (u16*)(ws + 2 * MB);       //  2MB: [8][32][4096] u16 tile image
  u16* vt_img = (u16*)(ws + 4 * MB);       //  4MB: [8][32][4096] u16 tile image
  u16* wt_img = (u16*)(ws + 6 * MB);       //  6MB: 295KB packed swizzled weights
  float* out = (float*)d_out;

  prepw_kernel<<<576, 256, 0, stream>>>(Wq, Wk, Wv, wt_img);
  proj_kernel<<<512, 512, 0, stream>>>(x, wt_img, q_ws, k_img, vt_img);
  attn_kernel<<<1024, 512, 0, stream>>>(q_ws, k_img, vt_img, out);
}

// Round 19
// 42.095 us; speedup vs baseline: 1.2781x; 1.2781x over previous
//
#include <hip/hip_runtime.h>
#include <hip/hip_bf16.h>

typedef unsigned short u16;
typedef unsigned int u32;
typedef __bf16 bf16;
typedef bf16 bf16x8 __attribute__((ext_vector_type(8)));
typedef float f32x4 __attribute__((ext_vector_type(4)));

#define B_ 8
#define T_ 2048
#define C_ 768
#define MB 1048576ull
#define SCALE_Q 0.1803368867f   /* 0.125 * log2(e): folds 1/sqrt(64) and exp->exp2 */
#define NEG_INF (-__builtin_inff())

#define AS1 __attribute__((address_space(1)))
#define AS3 __attribute__((address_space(3)))

__device__ __forceinline__ void g2l16(const void* g, void* l) {
  __builtin_amdgcn_global_load_lds((AS1 const void*)g, (AS3 void*)l, 16, 0, 0);
}
__device__ __forceinline__ u16 bf2u(bf16 h) {
  union { bf16 h; u16 u; } x; x.h = h; return x.u;
}
#define MFMA16(A, B, C) __builtin_amdgcn_mfma_f32_16x16x32_bf16((A), (B), (C), 0, 0, 0)
#define SBAR() __builtin_amdgcn_sched_barrier(0)
#define BARRIER() do { SBAR(); __builtin_amdgcn_s_barrier(); SBAR(); } while (0)

// ---------------------------------------------------------------------------
// Kernel 1: pre-swizzled Wt image, DOUBLE-STEP packed. (Unchanged.)
// ---------------------------------------------------------------------------
__global__ __launch_bounds__(256) void prepw_kernel(const float* __restrict__ Wq,
                                                    const float* __restrict__ Wk,
                                                    const float* __restrict__ Wv,
                                                    u16* __restrict__ wt_img) {
  int tid = blockIdx.x * 256 + threadIdx.x;        // 3*768*64 = 147456 exactly
  int jj = tid & 63;
  int k  = (tid >> 6) % C_;
  int m  = tid / (64 * C_);
  const float* W = (m == 0) ? Wq : (m == 1 ? Wk : Wv);
  bf16 hv = (bf16)W[k * 64 + jj];
  int s2 = k >> 6, kk2 = k & 63, j = m * 64 + jj;
  int byteoff = (s2 * 192 + j) * 128 + ((2 * kk2) ^ ((j & 7) << 4));
  *(u16*)((char*)wt_img + byteoff) = bf2u(hv);
}

// ---------------------------------------------------------------------------
// Kernel 2: projections, 2 BLOCKS/CU. (Round-17 proven version, unchanged.)
// ---------------------------------------------------------------------------
__global__ __launch_bounds__(512) void proj_kernel(const float* __restrict__ x,
                                                   const u16* __restrict__ wt_img,
                                                   u16* __restrict__ q_ws,
                                                   u16* __restrict__ k_img,
                                                   u16* __restrict__ vt_img) {
  __shared__ __align__(16) char xt[2][8192];       // [half][32 rows][128B] f32, swizzled
  __shared__ __align__(16) char wt[2][24576];
  int tid = threadIdx.x, lane = tid & 63, w = tid >> 6;
  int wm = w & 1, wn = w >> 1;           // wm: 16-row half; wn: 48-col band
  int r0 = blockIdx.x * 32;
  int c = lane & 15, g = lane >> 4;

  f32x4 acc[3];
#pragma unroll
  for (int i = 0; i < 3; ++i) acc[i] = (f32x4){0.f, 0.f, 0.f, 0.f};

  int xrow = (tid >> 3) & 31, xch = tid & 7, xhalf = tid >> 8;
  const float* srcx = x + (size_t)(r0 + xrow) * C_ + xhalf * 32 + ((xch ^ (xrow & 7)) << 2);

  auto STAGE = [&](int s, int bs) {
    const char* wsrc = (const char*)wt_img + s * 24576;
#pragma unroll
    for (int i = 0; i < 3; ++i)
      g2l16(wsrc + (i * 512 + tid) * 16, wt[bs] + (i * 512 + tid) * 16);
    g2l16(srcx + s * 64, xt[bs] + tid * 16);
  };

  STAGE(0, 0);

  int arow = wm * 16 + c;
  int ax = arow & 7;

  for (int s2 = 0; s2 < 12; ++s2) {
    int cur = s2 & 1;
    if (s2 < 11) {
      STAGE(s2 + 1, cur ^ 1);
      asm volatile("s_waitcnt vmcnt(4)" ::: "memory");   // stage(s2) landed
    } else {
      asm volatile("s_waitcnt vmcnt(0)" ::: "memory");
    }
    BARRIER();                           // stage(s2) certified landed (all waves)
    const char* x0 = xt[cur] + arow * 128;
    const char* x1 = x0 + 4096;
    f32x4 f0 = *(const f32x4*)(x0 + (((2 * g)     ^ ax) << 4));
    f32x4 f1 = *(const f32x4*)(x0 + (((2 * g + 1) ^ ax) << 4));
    f32x4 f2 = *(const f32x4*)(x1 + (((2 * g)     ^ ax) << 4));
    f32x4 f3 = *(const f32x4*)(x1 + (((2 * g + 1) ^ ax) << 4));
    bf16x8 af0, af1;
    af0[0] = (bf16)f0[0]; af0[1] = (bf16)f0[1]; af0[2] = (bf16)f0[2]; af0[3] = (bf16)f0[3];
    af0[4] = (bf16)f1[0]; af0[5] = (bf16)f1[1]; af0[6] = (bf16)f1[2]; af0[7] = (bf16)f1[3];
    af1[0] = (bf16)f2[0]; af1[1] = (bf16)f2[1]; af1[2] = (bf16)f2[2]; af1[3] = (bf16)f2[3];
    af1[4] = (bf16)f3[0]; af1[5] = (bf16)f3[1]; af1[6] = (bf16)f3[2]; af1[7] = (bf16)f3[3];
    const char* bb = wt[cur];
#pragma unroll
    for (int nt = 0; nt < 3; ++nt) {
      int brow = wn * 48 + nt * 16 + c;
      const char* br = bb + brow * 128;
      int bx = (brow & 7) << 4;
      bf16x8 b0 = *(const bf16x8*)(br + ((16 * g) ^ bx));
      bf16x8 b1 = *(const bf16x8*)(br + ((64 + 16 * g) ^ bx));
      acc[nt] = MFMA16(af0, b0, acc[nt]);
      acc[nt] = MFMA16(af1, b1, acc[nt]);
    }
    if (s2 < 11) {
      asm volatile("s_waitcnt lgkmcnt(0)" ::: "memory");
      BARRIER();                         // readers done -> buffer cur reusable
    }
  }

  // epilogue: D layout col = lane&15, row = (lane>>4)*4 + reg
#pragma unroll
  for (int nt = 0; nt < 3; ++nt) {
    int gc = wn * 48 + nt * 16;
    int m = gc >> 6;
    int h = (gc & 63) + c;
#pragma unroll
    for (int reg = 0; reg < 4; ++reg) {
      int r = r0 + wm * 16 + g * 4 + reg;   // token index
      float val = acc[nt][reg];
      int bb2 = r >> 11, rr = r & 2047, t = rr >> 6;
      if (m == 0) {
        q_ws[(size_t)r * 64 + h] = bf2u((bf16)(val * SCALE_Q));
      } else if (m == 1) {
        int ntk = (rr >> 4) & 3, ck = rr & 15;
        int jp = h >> 5, gg = (h >> 3) & 3, jj = h & 7;
        k_img[((size_t)(bb2 * 32 + t)) * 4096 + ntk * 1024 + jp * 512 + gg * 128 + ck * 8 + jj] = bf2u((bf16)val);
      } else {
        int ht = h >> 4, cv = h & 15;
        int jpv = (rr >> 5) & 1, gv = (rr >> 3) & 3, jv = rr & 7;
        vt_img[((size_t)(bb2 * 32 + t)) * 4096 + ht * 1024 + jpv * 512 + gv * 128 + cv * 8 + jv] = bf2u((bf16)val);
      }
    }
  }
}

// ---------------------------------------------------------------------------
// Kernel 3: causal flash attention, FUSED split-KV + in-LDS merge.
// Round-17 tile body (transient kf, SBARs intact — VGPR-safe), with ONE
// change: LPT dispatch order (heavy q-tiles first).
// ---------------------------------------------------------------------------
__device__ __forceinline__ void tile_body2(int t, int t0, int nkt, int q0,
                                           const u16* kbase, const u16* vbase,
                                           const bf16x8& qb0, const bf16x8& qb1,
                                           int c, int g, char* pw,
                                           f32x4 (&accO)[4], float& mrun, float& lrun) {
  // K fragments (B-op rows = kpos), contiguous loads; kf dies after QK^T
  bf16x8 kf[4][2];
#pragma unroll
  for (int nt = 0; nt < 4; ++nt)
#pragma unroll
    for (int jp = 0; jp < 2; ++jp)
      kf[nt][jp] = *(const bf16x8*)(kbase + (size_t)t * 4096 + nt * 1024 + jp * 512);
  SBAR();
  // S^T[kpos][q] = K . Q^T   (rows = kpos, cols = q = lane&15)
  f32x4 st[4];
#pragma unroll
  for (int nt = 0; nt < 4; ++nt) {
    f32x4 z = (f32x4){0.f, 0.f, 0.f, 0.f};
    z = MFMA16(kf[nt][0], qb0, z);
    st[nt] = MFMA16(kf[nt][1], qb1, z);
  }
  // V half 0 (kv slots 0-31) issues while softmax runs
  bf16x8 vf[4];
#pragma unroll
  for (int ht = 0; ht < 4; ++ht)
    vf[ht] = *(const bf16x8*)(vbase + (size_t)t * 4096 + ht * 1024);
  SBAR();
  int tt = t0 + t;
  if (tt == nkt - 1) {   // diagonal tile: mask kpos > q
    int qg = q0 + c, kb2 = tt * 64 + g * 4;
#pragma unroll
    for (int nt = 0; nt < 4; ++nt)
#pragma unroll
      for (int reg = 0; reg < 4; ++reg)
        if (kb2 + nt * 16 + reg > qg) st[nt][reg] = NEG_INF;
  }
  // lane-local softmax over 16 held kpos + cross-group (xor16, xor32)
  float smax = st[0][0];
#pragma unroll
  for (int nt = 0; nt < 4; ++nt)
#pragma unroll
    for (int reg = 0; reg < 4; ++reg) smax = fmaxf(smax, st[nt][reg]);
  smax = fmaxf(smax, __shfl_xor(smax, 16));
  smax = fmaxf(smax, __shfl_xor(smax, 32));
  float mnew = fmaxf(mrun, smax);
  float sf = exp2f(mrun - mnew);
  float rsum = 0.f;
  u32 pk[4][2];
#pragma unroll
  for (int nt = 0; nt < 4; ++nt)
#pragma unroll
    for (int jp = 0; jp < 2; ++jp) {
      float p0 = exp2f(st[nt][2 * jp] - mnew);
      float p1 = exp2f(st[nt][2 * jp + 1] - mnew);
      rsum += p0 + p1;
      pk[nt][jp] = (u32)bf2u((bf16)p0) | ((u32)bf2u((bf16)p1) << 16);
    }
  rsum += __shfl_xor(rsum, 16);
  rsum += __shfl_xor(rsum, 32);
  lrun = lrun * sf + rsum;
  mrun = mnew;
#pragma unroll
  for (int ht = 0; ht < 4; ++ht) accO[ht] *= sf;
  // P (q-row c, 64 kpos) -> wave-private swizzled LDS row, packed b32 writes
  int swz = (c & 7) << 4;
#pragma unroll
  for (int nt = 0; nt < 4; ++nt)
#pragma unroll
    for (int jp = 0; jp < 2; ++jp) {
      int kpos = nt * 16 + g * 4 + 2 * jp;
      *(u32*)(pw + ((2 * kpos) ^ swz)) = pk[nt][jp];
    }
  // PV half 0
  bf16x8 pf0 = *(const bf16x8*)(pw + ((16 * g) ^ swz));
#pragma unroll
  for (int ht = 0; ht < 4; ++ht)
    accO[ht] = MFMA16(vf[ht], pf0, accO[ht]);
  // V half 1 (kv slots 32-63), PV half 1
#pragma unroll
  for (int ht = 0; ht < 4; ++ht)
    vf[ht] = *(const bf16x8*)(vbase + (size_t)t * 4096 + ht * 1024 + 512);
  SBAR();
  bf16x8 pf1 = *(const bf16x8*)(pw + ((64 + 16 * g) ^ swz));
#pragma unroll
  for (int ht = 0; ht < 4; ++ht)
    accO[ht] = MFMA16(vf[ht], pf1, accO[ht]);
}

__global__ __launch_bounds__(512, 4) void attn_kernel(const u16* __restrict__ q_ws,
                                                      const u16* __restrict__ k_img,
                                                      const u16* __restrict__ vt_img,
                                                      float* __restrict__ out) {
  __shared__ __align__(16) char sP[8 * 2048];       // wave-private P tiles
  __shared__ float po_s[8][64][17];                 // padded: conflict-free both ways
  __shared__ float2 ml_s[8][16];
  int tid = threadIdx.x, lane = tid & 63, w = tid >> 6;
  int bid = blockIdx.x;
  int b = bid & 7;                       // batch -> XCD
  int qt = 127 - (bid >> 3);             // LPT: heavy q-tiles dispatch FIRST
  int nkt = (qt >> 2) + 1;               // 1..32 KV tiles
  int CH = (nkt + 7) >> 3;               // 1..4 tiles per wave
  int t0 = w * CH;
  int n = nkt - t0; if (n < 0) n = 0; if (n > CH) n = CH;
  int q0 = qt * 16;
  int c = lane & 15, g = lane >> 4;

  // Q as B-operand: col = q = c, k(h) = 8g+j; q pre-scaled by 0.125*log2e
  const u16* qb_p = q_ws + ((size_t)b * T_ + q0 + c) * 64 + 8 * g;
  bf16x8 qb0 = *(const bf16x8*)qb_p;
  bf16x8 qb1 = *(const bf16x8*)(qb_p + 32);

  const u16* kbase = k_img + ((size_t)(b * 32 + t0)) * 4096 + lane * 8;
  const u16* vbase = vt_img + ((size_t)(b * 32 + t0)) * 4096 + lane * 8;

  f32x4 accO[4];
#pragma unroll
  for (int i = 0; i < 4; ++i) accO[i] = (f32x4){0.f, 0.f, 0.f, 0.f};
  float mrun = NEG_INF, lrun = 0.f;
  char* pw = sP + w * 2048 + c * 128;

  if (n > 0) tile_body2(0, t0, nkt, q0, kbase, vbase, qb0, qb1, c, g, pw, accO, mrun, lrun);
  if (n > 1) tile_body2(1, t0, nkt, q0, kbase, vbase, qb0, qb1, c, g, pw, accO, mrun, lrun);
  if (n > 2) tile_body2(2, t0, nkt, q0, kbase, vbase, qb0, qb1, c, g, pw, accO, mrun, lrun);
  if (n > 3) tile_body2(3, t0, nkt, q0, kbase, vbase, qb0, qb1, c, g, pw, accO, mrun, lrun);

  // publish partials to LDS (active waves only)
  if (n > 0) {
#pragma unroll
    for (int ht = 0; ht < 4; ++ht)
#pragma unroll
      for (int reg = 0; reg < 4; ++reg)
        po_s[w][ht * 16 + g * 4 + reg][c] = accO[ht][reg];
    if (g == 0) ml_s[w][c] = make_float2(mrun, lrun);
  }
  __syncthreads();

  // in-block merge: wave w handles q-rows {w, w+8}; lane holds h = lane.
  int nact = (nkt + CH - 1) / CH;        // number of active chunk waves
#pragma unroll
  for (int half = 0; half < 2; ++half) {
    int qq = w + half * 8;
    float M = NEG_INF;
#pragma unroll
    for (int ci = 0; ci < 8; ++ci)
      if (ci < nact) M = fmaxf(M, ml_s[ci][qq].x);
    float L = 0.f, s = 0.f;
#pragma unroll
    for (int ci = 0; ci < 8; ++ci)
      if (ci < nact) {
        float2 mlv = ml_s[ci][qq];
        float wg = exp2f(mlv.x - M);
        L += wg * mlv.y;
        s += wg * po_s[ci][lane][qq];
      }
    out[((size_t)b * T_ + q0 + qq) * 64 + lane] = s / L;
  }
}

// ---------------------------------------------------------------------------
extern "C" void kernel_launch(void* const* d_in, const int* in_sizes, int n_in,
                              void* d_out, int out_size, void* d_ws, size_t ws_size,
                              hipStream_t stream) {
  const float* x  = (const float*)d_in[0];
  const float* Wk = (const float*)d_in[1];
  const float* Wq = (const float*)d_in[2];
  const float* Wv = (const float*)d_in[3];
  char* ws = (char*)d_ws;
  u16* q_ws   = (u16*)(ws);                //  0MB: [16384][64] bf16 (q * 0.125*log2e)
  u16* k_img  = (u16*)(ws + 2 * MB);       //  2MB: [8][32][4096] u16 tile image
  u16* vt_img = (u16*)(ws + 4 * MB);       //  4MB: [8][32][4096] u16 tile image
  u16* wt_img = (u16*)(ws + 6 * MB);       //  6MB: 295KB packed swizzled weights
  float* out = (float*)d_out;

  prepw_kernel<<<576, 256, 0, stream>>>(Wq, Wk, Wv, wt_img);
  proj_kernel<<<512, 512, 0, stream>>>(x, wt_img, q_ws, k_img, vt_img);
  attn_kernel<<<1024, 512, 0, stream>>>(q_ws, k_img, vt_img, out);
}